// Round 2
// baseline (104.029 us; speedup 1.0000x reference)
//
#include <hip/hip_runtime.h>

// Diversity2: mean(0.3 * pearson_corr(softmax(o1/T), softmax(o2/T), axis=1))
//
// Identities used:
//  (1) corr is invariant to per-row positive scaling and shift -> softmax
//      normalization and max-subtraction drop out: corr(p1,p2) ==
//      corr(exp(o1/T), exp(o2/T)).
//  (2) shift again: use x = exp(o/T) - 1 (exact Sterbenz subtraction since
//      exp(o/T) in [0.78,1.32]). This centers x near 0 so fp32 accumulation
//      of {Sx,Sy,Sxx,Syy,Sxy} has no catastrophic cancellation
//      (Sxx ~ 2.5, (Sx)^2/C ~ 0.003). fp64 only for the per-row epilogue.
//
// Structure: per-wave barrier-free software pipeline. Each wave owns 16 KB of
// LDS (2 buffers x [o1-row | o2-row], 8 KB each), stages the NEXT row with
// 8x global_load_lds(width=16) while computing the CURRENT row, synced with
// counted `s_waitcnt vmcnt(8)` (never drained to 0 in-loop). In-flight bytes
// live in LDS, not VGPRs -> 8 waves/CU x 8 KB = 64 KB outstanding per CU,
// far above the ~9 KB Little's-law requirement for full HBM BW.

#define N_ROWS   65536
#define N_C      1000
#define NBLOCKS  2048
#define WPB      4          // waves per block
#define RPW      8          // rows per wave: 65536 / (2048*4)

__device__ __forceinline__ void gload16(const float* g, float* s) {
    __builtin_amdgcn_global_load_lds(
        (const __attribute__((address_space(1))) void*)g,
        (__attribute__((address_space(3))) void*)s, 16, 0, 0);
}

// Stage one row (both matrices) into an 8 KB LDS buffer.
// Row = 1000 floats = 250 float4; padded to 256 float4 slots per matrix.
// Chunk k covers float4 indices [64k, 64k+63]; k=3 is valid only for j<=249
// (lane<58); for lanes 58..63 it reads the first 96 B of the NEXT row (safe,
// in-bounds) except at the very last row, where those lanes are masked.
__device__ __forceinline__ void stage_row(const float* __restrict__ o1,
                                          const float* __restrict__ o2,
                                          long row, float* dst, int lane) {
    const float* r1 = o1 + row * (long)N_C;
    const float* r2 = o2 + row * (long)N_C;
    const int l4 = lane * 4;
    gload16(r1 + l4,       dst);
    gload16(r1 + 256 + l4, dst + 256);
    gload16(r1 + 512 + l4, dst + 512);
    gload16(r2 + l4,       dst + 1024);
    gload16(r2 + 256 + l4, dst + 1280);
    gload16(r2 + 512 + l4, dst + 1536);
    bool tail_ok = (lane < 58) || (row + 1 < (long)N_ROWS);
    if (tail_ok) {                      // never all-false -> always 8 insts
        gload16(r1 + 768 + l4, dst + 768);
        gload16(r2 + 768 + l4, dst + 1792);
    }
}

// Compute per-row Pearson cost from an LDS buffer (A at dst, B at dst+1024).
__device__ __forceinline__ double row_cost(const float* buf, int lane) {
    const float4* A = reinterpret_cast<const float4*>(buf);
    const float4* B = reinterpret_cast<const float4*>(buf + 1024);
    constexpr float INV_T = 1.0f / 20.0f;
    float sx = 0.f, sy = 0.f, sxx = 0.f, syy = 0.f, sxy = 0.f;
    #pragma unroll
    for (int k = 0; k < 4; ++k) {
        float4 a = A[k * 64 + lane];
        float4 b = B[k * 64 + lane];
        const bool ok = (k < 3) || (lane < 58);
        float av[4] = {a.x, a.y, a.z, a.w};
        float bv[4] = {b.x, b.y, b.z, b.w};
        #pragma unroll
        for (int e = 0; e < 4; ++e) {
            // zero the INPUT for invalid slots: exp(0)-1 == 0 contributes
            // nothing to any sum (also immune to garbage/NaN in LDS pad).
            float va = ok ? av[e] : 0.0f;
            float vb = ok ? bv[e] : 0.0f;
            float x = __expf(va * INV_T) - 1.0f;
            float y = __expf(vb * INV_T) - 1.0f;
            sx += x;  sy += y;
            sxx = fmaf(x, x, sxx);
            syy = fmaf(y, y, syy);
            sxy = fmaf(x, y, sxy);
        }
    }
    #pragma unroll
    for (int off = 32; off; off >>= 1) {
        sx  += __shfl_xor(sx,  off, 64);
        sy  += __shfl_xor(sy,  off, 64);
        sxx += __shfl_xor(sxx, off, 64);
        syy += __shfl_xor(syy, off, 64);
        sxy += __shfl_xor(sxy, off, 64);
    }
    constexpr double invC = 1.0 / (double)N_C;
    double dx = (double)sx, dy = (double)sy;
    double num = (double)sxy - dx * dy * invC;
    double vx  = (double)sxx - dx * dx * invC;
    double vy  = (double)syy - dy * dy * invC;
    return num / sqrt(vx * vy);
}

__global__ __launch_bounds__(256) void div2_stage1(
        const float* __restrict__ o1, const float* __restrict__ o2,
        double* __restrict__ ws) {
    __shared__ float lds[WPB][2][2048];   // 64 KB: per-wave 2 x 8 KB buffers
    const int wave = threadIdx.x >> 6;
    const int lane = threadIdx.x & 63;
    const int gw   = blockIdx.x * WPB + wave;
    const long r0  = (long)gw * RPW;

    float* buf0 = &lds[wave][0][0];
    float* buf1 = &lds[wave][1][0];

    stage_row(o1, o2, r0, buf0, lane);    // prologue: fill buffer 0

    double acc = 0.0;
    #pragma unroll 1
    for (int p = 0; p < RPW; ++p) {
        float* cur = (p & 1) ? buf1 : buf0;
        float* nxt = (p & 1) ? buf0 : buf1;
        if (p + 1 < RPW) {
            stage_row(o1, o2, r0 + p + 1, nxt, lane);  // prefetch next row
            // counted wait: current row's 8 loads done, next row's 8 in flight
            asm volatile("s_waitcnt vmcnt(8)" ::: "memory");
        } else {
            asm volatile("s_waitcnt vmcnt(0)" ::: "memory");
        }
        acc += row_cost(cur, lane);
    }

    // block-level combine (pipeline is done; reuse LDS)
    __syncthreads();
    double* dred = reinterpret_cast<double*>(&lds[0][0][0]);
    if (lane == 0) dred[wave] = acc;
    __syncthreads();
    if (threadIdx.x == 0)
        ws[blockIdx.x] = dred[0] + dred[1] + dred[2] + dred[3];
}

__global__ __launch_bounds__(256) void div2_stage2(
        const double* __restrict__ ws, int n, float* __restrict__ out) {
    double s = 0.0;
    for (int i = threadIdx.x; i < n; i += 256) s += ws[i];
    #pragma unroll
    for (int off = 32; off; off >>= 1) s += __shfl_xor(s, off, 64);
    __shared__ double lds[4];
    const int wave = threadIdx.x >> 6;
    const int lane = threadIdx.x & 63;
    if (lane == 0) lds[wave] = s;
    __syncthreads();
    if (threadIdx.x == 0) {
        double t = lds[0] + lds[1] + lds[2] + lds[3];
        out[0] = (float)(t * (0.3 / (double)N_ROWS));
    }
}

extern "C" void kernel_launch(void* const* d_in, const int* in_sizes, int n_in,
                              void* d_out, int out_size, void* d_ws, size_t ws_size,
                              hipStream_t stream) {
    const float* o1 = (const float*)d_in[0];
    const float* o2 = (const float*)d_in[1];
    // d_in[2] (targets) is unused by the reference.
    float* out = (float*)d_out;
    double* ws = (double*)d_ws;   // 2048 doubles = 16 KB (proven to fit)

    div2_stage1<<<NBLOCKS, 256, 0, stream>>>(o1, o2, ws);
    div2_stage2<<<1, 256, 0, stream>>>(ws, NBLOCKS, out);
}